// Round 8
// baseline (511.747 us; speedup 1.0000x reference)
//
#include <hip/hip_runtime.h>

#define LAT_SHAPE 1801
#define LON_SHAPE 3600
#define NPTS 2000000
#define TILES_X 29            // ceil(3600/128)
#define TILES_Y 57            // ceil(1801/32)
#define NB (TILES_X * TILES_Y)  // 1653 buckets: 32-row x 128-col tiles

typedef float f32x4 __attribute__((ext_vector_type(4)));

// FROZEN MATH (bit-exact vs np golden, round 5): f32, *10.0f, ties-even.
__device__ __forceinline__ void coord2idx(float lat, float lon, int& yi, int& xi) {
    float qy = (90.0f - lat) * 10.0f;
    float qx = lon * 10.0f;
    yi = (int)rintf(qy);
    xi = (int)rintf(qx);
    yi = min(max(yi, 0), LAT_SHAPE - 1);
    xi = min(max(xi, 0), LON_SHAPE - 1);
}

__device__ __forceinline__ int bucket_of(int yi, int xi) {
    return (yi >> 5) * TILES_X + (xi >> 7);
}

// ---- Pass A: per-tile histogram (LDS-aggregated) ----
__global__ __launch_bounds__(256) void hist_k(const float2* __restrict__ x, int n,
                                              unsigned* __restrict__ counts) {
    __shared__ unsigned h[NB];
    for (int k = threadIdx.x; k < NB; k += 256) h[k] = 0;
    __syncthreads();
    int stride = gridDim.x * 256;
    for (int i = blockIdx.x * 256 + threadIdx.x; i < n; i += stride) {
        float2 p = x[i];
        int yi, xi; coord2idx(p.x, p.y, yi, xi);
        atomicAdd(&h[bucket_of(yi, xi)], 1u);
    }
    __syncthreads();
    for (int k = threadIdx.x; k < NB; k += 256)
        if (h[k]) atomicAdd(&counts[k], h[k]);
}

// ---- Pass B: serial exclusive scan (1653 elements, ~us) ----
__global__ void scan_k(const unsigned* __restrict__ counts,
                       unsigned* __restrict__ cursors) {
    if (threadIdx.x == 0) {
        unsigned acc = 0;
        for (int k = 0; k < NB; ++k) { cursors[k] = acc; acc += counts[k]; }
    }
}

// ---- Pass C: scatter records into bucket order ----
// Record: .x = orig point index, .y = (yi<<12)|xi. Order within a bucket is
// atomically raced (non-deterministic) but the OUTPUT is order-independent.
__global__ __launch_bounds__(256) void scatter_k(const float2* __restrict__ x, int n,
                                                 unsigned* __restrict__ cursors,
                                                 uint2* __restrict__ rec) {
    int stride = gridDim.x * 256;
    for (int i = blockIdx.x * 256 + threadIdx.x; i < n; i += stride) {
        float2 p = x[i];
        int yi, xi; coord2idx(p.x, p.y, yi, xi);
        unsigned pos = atomicAdd(&cursors[bucket_of(yi, xi)], 1u);
        rec[pos] = make_uint2((unsigned)i, ((unsigned)yi << 12) | (unsigned)xi);
    }
}

// ---- Pass D: main compute over sorted records ----
__global__ __launch_bounds__(256) void main_k(
    const uint2* __restrict__ rec, int n, int nwg,
    const float* __restrict__ g0, const float* __restrict__ g1,
    const float* __restrict__ g2, const float* __restrict__ g3,
    const float* __restrict__ g4, const float* __restrict__ g5,
    const float* __restrict__ g6, const float* __restrict__ g7,
    float* __restrict__ out)
{
#pragma clang fp contract(off)
    __shared__ float g6s[1653];   // 29 x 57
    __shared__ float g7s[435];    // 15 x 29
    for (int k = threadIdx.x; k < 1653; k += 256) g6s[k] = g6[k];
    for (int k = threadIdx.x; k < 435; k += 256) g7s[k] = g7[k];
    __syncthreads();

    // Chunked bijective XCD swizzle (m204): consecutive sorted ranges stay on
    // one XCD so each tile's grid lines are fetched into exactly one L2.
    int orig = blockIdx.x;
    int xcd = orig & 7;
    int q = nwg >> 3, r = nwg & 7;
    int wg = (xcd < r ? xcd * (q + 1) : r * (q + 1) + (xcd - r) * q) + (orig >> 3);
    int i = wg * 256 + threadIdx.x;
    if (i >= n) return;

    uint2 rc = rec[i];
    int yi = (int)(rc.y >> 12);
    int xi = (int)(rc.y & 4095u);

    float res[8];
    // Level 0: scale exactly 1.0 -> blend collapses to v00. Single gather.
    res[0] = g0[yi * LON_SHAPE + xi];

    constexpr int H[8] = {1801, 901, 451, 226, 113, 57, 29, 15};
    constexpr int W[8] = {3600, 1800, 900, 450, 225, 113, 57, 29};
    const float yif = (float)yi;
    const float xif = (float)xi;

    auto bilin = [&](auto g, int Hi, int Wi, float sy_scale, float sx_scale) -> float {
#pragma clang fp contract(off)
        float sy = fmaxf((yif + 0.5f) * sy_scale - 0.5f, 0.0f);
        float sx = fmaxf((xif + 0.5f) * sx_scale - 0.5f, 0.0f);
        int y0 = (int)sy;
        int x0 = (int)sx;
        float wy = sy - (float)y0;
        float wx = sx - (float)x0;
        int y1 = min(y0 + 1, Hi - 1);
        int x1 = min(x0 + 1, Wi - 1);
        float v00 = g[y0 * Wi + x0];
        float v01 = g[y0 * Wi + x1];
        float v10 = g[y1 * Wi + x0];
        float v11 = g[y1 * Wi + x1];
        float omwy = 1.0f - wy, omwx = 1.0f - wx;
        return v00 * omwy * omwx + v01 * omwy * wx
             + v10 * wy * omwx + v11 * wy * wx;
    };

#define SC(i, dim, tot) ((float)((double)dim[i] / (double)tot))
    res[1] = bilin(g1, H[1], W[1], SC(1, H, LAT_SHAPE), SC(1, W, LON_SHAPE));
    res[2] = bilin(g2, H[2], W[2], SC(2, H, LAT_SHAPE), SC(2, W, LON_SHAPE));
    res[3] = bilin(g3, H[3], W[3], SC(3, H, LAT_SHAPE), SC(3, W, LON_SHAPE));
    res[4] = bilin(g4, H[4], W[4], SC(4, H, LAT_SHAPE), SC(4, W, LON_SHAPE));
    res[5] = bilin(g5, H[5], W[5], SC(5, H, LAT_SHAPE), SC(5, W, LON_SHAPE));
    res[6] = bilin((const float*)g6s, H[6], W[6], SC(6, H, LAT_SHAPE), SC(6, W, LON_SHAPE));
    res[7] = bilin((const float*)g7s, H[7], W[7], SC(7, H, LAT_SHAPE), SC(7, W, LON_SHAPE));
#undef SC

    f32x4 lo = {res[0], res[1], res[2], res[3]};
    f32x4 hi = {res[4], res[5], res[6], res[7]};
    float* op = out + (size_t)rc.x * 8;
    __builtin_nontemporal_store(lo, (f32x4*)op);
    __builtin_nontemporal_store(hi, (f32x4*)(op + 4));
}

// ---- Fallback: round-7 direct kernel (used if ws too small) ----
__global__ __launch_bounds__(256) void le_kernel(
    const float2* __restrict__ x,
    const float* __restrict__ g0, const float* __restrict__ g1,
    const float* __restrict__ g2, const float* __restrict__ g3,
    const float* __restrict__ g4, const float* __restrict__ g5,
    const float* __restrict__ g6, const float* __restrict__ g7,
    float* __restrict__ out, int n)
{
#pragma clang fp contract(off)
    __shared__ float g6s[1653];
    __shared__ float g7s[435];
    __shared__ f32x4 obuf[512];
    for (int k = threadIdx.x; k < 1653; k += 256) g6s[k] = g6[k];
    for (int k = threadIdx.x; k < 435; k += 256) g7s[k] = g7[k];
    __syncthreads();

    int idx = blockIdx.x * blockDim.x + threadIdx.x;
    int cidx = min(idx, n - 1);
    float2 p = x[cidx];
    int yi, xi; coord2idx(p.x, p.y, yi, xi);

    float res[8];
    res[0] = g0[yi * LON_SHAPE + xi];
    constexpr int H[8] = {1801, 901, 451, 226, 113, 57, 29, 15};
    constexpr int W[8] = {3600, 1800, 900, 450, 225, 113, 57, 29};
    const float yif = (float)yi;
    const float xif = (float)xi;
    auto bilin = [&](auto g, int Hi, int Wi, float sy_scale, float sx_scale) -> float {
#pragma clang fp contract(off)
        float sy = fmaxf((yif + 0.5f) * sy_scale - 0.5f, 0.0f);
        float sx = fmaxf((xif + 0.5f) * sx_scale - 0.5f, 0.0f);
        int y0 = (int)sy; int x0 = (int)sx;
        float wy = sy - (float)y0; float wx = sx - (float)x0;
        int y1 = min(y0 + 1, Hi - 1); int x1 = min(x0 + 1, Wi - 1);
        float v00 = g[y0 * Wi + x0]; float v01 = g[y0 * Wi + x1];
        float v10 = g[y1 * Wi + x0]; float v11 = g[y1 * Wi + x1];
        float omwy = 1.0f - wy, omwx = 1.0f - wx;
        return v00 * omwy * omwx + v01 * omwy * wx + v10 * wy * omwx + v11 * wy * wx;
    };
#define SC(i, dim, tot) ((float)((double)dim[i] / (double)tot))
    res[1] = bilin(g1, H[1], W[1], SC(1, H, LAT_SHAPE), SC(1, W, LON_SHAPE));
    res[2] = bilin(g2, H[2], W[2], SC(2, H, LAT_SHAPE), SC(2, W, LON_SHAPE));
    res[3] = bilin(g3, H[3], W[3], SC(3, H, LAT_SHAPE), SC(3, W, LON_SHAPE));
    res[4] = bilin(g4, H[4], W[4], SC(4, H, LAT_SHAPE), SC(4, W, LON_SHAPE));
    res[5] = bilin(g5, H[5], W[5], SC(5, H, LAT_SHAPE), SC(5, W, LON_SHAPE));
    res[6] = bilin((const float*)g6s, H[6], W[6], SC(6, H, LAT_SHAPE), SC(6, W, LON_SHAPE));
    res[7] = bilin((const float*)g7s, H[7], W[7], SC(7, H, LAT_SHAPE), SC(7, W, LON_SHAPE));
#undef SC
    f32x4 lo = {res[0], res[1], res[2], res[3]};
    f32x4 hi = {res[4], res[5], res[6], res[7]};
    obuf[2 * threadIdx.x] = lo;
    obuf[2 * threadIdx.x + 1] = hi;
    __syncthreads();
    const size_t total_f4 = (size_t)n * 2;
    const size_t base = (size_t)blockIdx.x * 512;
    f32x4* o4 = (f32x4*)out;
    int t = threadIdx.x;
    if (base + t < total_f4) __builtin_nontemporal_store(obuf[t], &o4[base + t]);
    if (base + 256 + t < total_f4) __builtin_nontemporal_store(obuf[256 + t], &o4[base + 256 + t]);
}

extern "C" void kernel_launch(void* const* d_in, const int* in_sizes, int n_in,
                              void* d_out, int out_size, void* d_ws, size_t ws_size,
                              hipStream_t stream) {
    const int GSZ[8] = {6483600, 1621800, 405900, 101700, 25425, 6441, 1653, 435};
    const float* xp = nullptr;
    const float* g[8] = {nullptr};
    int n = 0;
    for (int i = 0; i < n_in; ++i) {
        int s = in_sizes[i];
        if (s == 2 * NPTS) { xp = (const float*)d_in[i]; n = NPTS; continue; }
        for (int l = 0; l < 8; ++l)
            if (s == GSZ[l]) { g[l] = (const float*)d_in[i]; break; }
    }
    if (!xp) { xp = (const float*)d_in[0]; n = in_sizes[0] / 2; }
    for (int l = 0; l < 8; ++l)
        if (!g[l]) g[l] = (const float*)d_in[1 + l];

    const float2* x2 = (const float2*)xp;
    float* out = (float*)d_out;
    int nwg = (n + 255) / 256;

    // ws layout: counts[NB] | cursors[NB] | ... records at 64KB
    size_t need = 65536 + (size_t)n * 8;
    if (ws_size >= need && n > 0) {
        unsigned* counts = (unsigned*)d_ws;
        unsigned* cursors = counts + NB;
        uint2* rec = (uint2*)((char*)d_ws + 65536);
        hipMemsetAsync(counts, 0, NB * sizeof(unsigned), stream);
        hist_k<<<512, 256, 0, stream>>>(x2, n, counts);
        scan_k<<<1, 64, 0, stream>>>(counts, cursors);
        scatter_k<<<1024, 256, 0, stream>>>(x2, n, cursors, rec);
        main_k<<<nwg, 256, 0, stream>>>(rec, n, nwg, g[0], g[1], g[2], g[3],
                                        g[4], g[5], g[6], g[7], out);
    } else {
        le_kernel<<<nwg, 256, 0, stream>>>(x2, g[0], g[1], g[2], g[3], g[4],
                                           g[5], g[6], g[7], out, n);
    }
}

// Round 9
// 159.935 us; speedup vs baseline: 3.1997x; 3.1997x over previous
//
#include <hip/hip_runtime.h>

#define LAT_SHAPE 1801
#define LON_SHAPE 3600
#define NPTS 2000000

typedef float f32x4 __attribute__((ext_vector_type(4)));

__global__ __launch_bounds__(256, 8) void le_kernel(
    const float2* __restrict__ x,
    const float* __restrict__ g0, const float* __restrict__ g1,
    const float* __restrict__ g2, const float* __restrict__ g3,
    const float* __restrict__ g4, const float* __restrict__ g5,
    const float* __restrict__ g6, const float* __restrict__ g7,
    float* __restrict__ out, int n)
{
#pragma clang fp contract(off)
    // LDS: g6/g7 grids (8.3KB) + output packing buffer (8KB) -> 8 blocks/CU.
    __shared__ float g6s[1653];   // 29 x 57
    __shared__ float g7s[435];    // 15 x 29
    __shared__ f32x4 obuf[512];

    int idx = blockIdx.x * blockDim.x + threadIdx.x;
    int cidx = min(idx, n - 1);   // tail threads duplicate last point
    float2 p = x[cidx];           // issue x load before LDS staging (overlap)

    for (int k = threadIdx.x; k < 1653; k += 256) g6s[k] = g6[k];
    for (int k = threadIdx.x; k < 435; k += 256) g7s[k] = g7[k];
    // Barrier BEFORE the gather phase: its vmcnt(0) drain only covers the
    // cheap staging loads, never the 21 batched gathers below.
    __syncthreads();

    // FROZEN MATH (bit-exact vs np golden, round 5): f32, *10.0f, ties-even.
    int yi = (int)rintf((90.0f - p.x) * 10.0f);
    int xi = (int)rintf(p.y * 10.0f);
    yi = min(max(yi, 0), LAT_SHAPE - 1);
    xi = min(max(xi, 0), LON_SHAPE - 1);

    // ---- Phase 1: issue ALL global gathers before consuming any ----------
    // Level 0 (slowest, L2-miss likely): issue first, nontemporal (lines have
    // ~1-2 touches/XCD -> not worth L2 residency; frees capacity for g1/g2).
    float r0 = __builtin_nontemporal_load(&g0[yi * LON_SHAPE + xi]);

    constexpr int H[5] = {901, 451, 226, 113, 57};    // levels 1..5
    constexpr int W[5] = {1800, 900, 450, 225, 113};
    constexpr float SCY[5] = {
        (float)(901.0 / 1801.0), (float)(451.0 / 1801.0), (float)(226.0 / 1801.0),
        (float)(113.0 / 1801.0), (float)(57.0 / 1801.0)};
    constexpr float SCX[5] = {
        (float)(1800.0 / 3600.0), (float)(900.0 / 3600.0), (float)(450.0 / 3600.0),
        (float)(225.0 / 3600.0), (float)(113.0 / 3600.0)};

    const float* gg[5] = {g1, g2, g3, g4, g5};
    const float yif = (float)yi;
    const float xif = (float)xi;

    float vv[5][4];     // static-indexed after unroll -> registers
    float wyA[5], wxA[5];

#pragma unroll
    for (int i = 0; i < 5; ++i) {
        float sy = fmaxf((yif + 0.5f) * SCY[i] - 0.5f, 0.0f);
        float sx = fmaxf((xif + 0.5f) * SCX[i] - 0.5f, 0.0f);
        int y0 = (int)sy;            // floor: sy >= 0
        int x0 = (int)sx;
        wyA[i] = sy - (float)y0;
        wxA[i] = sx - (float)x0;
        int y1 = min(y0 + 1, H[i] - 1);
        int x1 = min(x0 + 1, W[i] - 1);
        const float* __restrict__ g = gg[i];
        vv[i][0] = g[y0 * W[i] + x0];
        vv[i][1] = g[y0 * W[i] + x1];
        vv[i][2] = g[y1 * W[i] + x0];
        vv[i][3] = g[y1 * W[i] + x1];
    }

    // ---- Phase 2: LDS levels 6..7 (lgkm waits only, vmem still in flight) --
    float res6, res7;
    {
        constexpr int HL[2] = {29, 15};
        constexpr int WL[2] = {57, 29};
        constexpr float LSY[2] = {(float)(29.0 / 1801.0), (float)(15.0 / 1801.0)};
        constexpr float LSX[2] = {(float)(57.0 / 3600.0), (float)(29.0 / 3600.0)};
        const float* ls[2] = {g6s, g7s};
        float r[2];
#pragma unroll
        for (int i = 0; i < 2; ++i) {
            float sy = fmaxf((yif + 0.5f) * LSY[i] - 0.5f, 0.0f);
            float sx = fmaxf((xif + 0.5f) * LSX[i] - 0.5f, 0.0f);
            int y0 = (int)sy;
            int x0 = (int)sx;
            float wy = sy - (float)y0;
            float wx = sx - (float)x0;
            int y1 = min(y0 + 1, HL[i] - 1);
            int x1 = min(x0 + 1, WL[i] - 1);
            const float* g = ls[i];
            float v00 = g[y0 * WL[i] + x0];
            float v01 = g[y0 * WL[i] + x1];
            float v10 = g[y1 * WL[i] + x0];
            float v11 = g[y1 * WL[i] + x1];
            float omwy = 1.0f - wy, omwx = 1.0f - wx;
            r[i] = v00 * omwy * omwx + v01 * omwy * wx
                 + v10 * wy * omwx + v11 * wy * wx;
        }
        res6 = r[0]; res7 = r[1];
    }

    // ---- Phase 3: blend levels 1..5 (consume in issue order) --------------
    float res[8];
    res[0] = r0;          // level 0: scale==1.0 -> blend collapses to v00
    res[6] = res6;
    res[7] = res7;
#pragma unroll
    for (int i = 0; i < 5; ++i) {
        float wy = wyA[i], wx = wxA[i];
        float omwy = 1.0f - wy, omwx = 1.0f - wx;
        res[1 + i] = vv[i][0] * omwy * omwx + vv[i][1] * omwy * wx
                   + vv[i][2] * wy * omwx + vv[i][3] * wy * wx;
    }

    // ---- Pack through LDS: each store covers a contiguous 1KB range -------
    f32x4 lo = {res[0], res[1], res[2], res[3]};
    f32x4 hi = {res[4], res[5], res[6], res[7]};
    obuf[2 * threadIdx.x]     = lo;
    obuf[2 * threadIdx.x + 1] = hi;
    __syncthreads();

    const size_t total_f4 = (size_t)n * 2;
    const size_t base = (size_t)blockIdx.x * 512;
    f32x4* o4 = (f32x4*)out;
    int t = threadIdx.x;
    if (base + t < total_f4)
        __builtin_nontemporal_store(obuf[t], &o4[base + t]);
    if (base + 256 + t < total_f4)
        __builtin_nontemporal_store(obuf[256 + t], &o4[base + 256 + t]);
}

extern "C" void kernel_launch(void* const* d_in, const int* in_sizes, int n_in,
                              void* d_out, int out_size, void* d_ws, size_t ws_size,
                              hipStream_t stream) {
    // Assign roles by unique element count (robust to input permutation).
    const int GSZ[8] = {6483600, 1621800, 405900, 101700, 25425, 6441, 1653, 435};
    const float* xp = nullptr;
    const float* g[8] = {nullptr};
    int n = 0;
    for (int i = 0; i < n_in; ++i) {
        int s = in_sizes[i];
        if (s == 2 * NPTS) { xp = (const float*)d_in[i]; n = NPTS; continue; }
        for (int l = 0; l < 8; ++l)
            if (s == GSZ[l]) { g[l] = (const float*)d_in[i]; break; }
    }
    if (!xp) { xp = (const float*)d_in[0]; n = in_sizes[0] / 2; }
    for (int l = 0; l < 8; ++l)
        if (!g[l]) g[l] = (const float*)d_in[1 + l];

    int blocks = (n + 255) / 256;
    le_kernel<<<blocks, 256, 0, stream>>>((const float2*)xp, g[0], g[1], g[2],
                                          g[3], g[4], g[5], g[6], g[7],
                                          (float*)d_out, n);
}